// Round 10
// baseline (253.069 us; speedup 1.0000x reference)
//
#include <hip/hip_runtime.h>
#include <hip/hip_bf16.h>

#define BB 32
#define NN 1025
#define CC 512
#define HH 8
#define HD 64
#define MM (BB * NN)        // 32800
#define MP 33024            // padded plane rows (258 * 128)
#define KK 512
#define SCALE 0.125f

typedef unsigned short u16;
typedef __attribute__((ext_vector_type(4))) unsigned short u16x4;
typedef __attribute__((ext_vector_type(8))) unsigned short u16x8;
typedef __attribute__((ext_vector_type(4))) float f32x4;
typedef __attribute__((ext_vector_type(8))) __bf16 bf16x8;

__device__ __forceinline__ u16 f2bf(float f) {
    unsigned u = __float_as_uint(f);
    unsigned r = (u + 0x7FFFu + ((u >> 16) & 1u)) >> 16;
    return (u16)r;
}
__device__ __forceinline__ float bf2f(u16 h) {
    return __uint_as_float((unsigned)h << 16);
}

__device__ __forceinline__ void gload16(const u16* g, u16* l) {
    __builtin_amdgcn_global_load_lds(
        (const __attribute__((address_space(1))) unsigned int*)g,
        (__attribute__((address_space(3))) unsigned int*)l, 16, 0, 0);
}

// pack 8 f32 -> 8 bf16 (RNE) via v_cvt_pk_bf16_f32
__device__ __forceinline__ u16x8 cvt8(f32x4 a, f32x4 b) {
    union { unsigned u[4]; u16x8 v; } r;
    asm("v_cvt_pk_bf16_f32 %0, %1, %2" : "=v"(r.u[0]) : "v"(a[0]), "v"(a[1]));
    asm("v_cvt_pk_bf16_f32 %0, %1, %2" : "=v"(r.u[1]) : "v"(a[2]), "v"(a[3]));
    asm("v_cvt_pk_bf16_f32 %0, %1, %2" : "=v"(r.u[2]) : "v"(b[0]), "v"(b[1]));
    asm("v_cvt_pk_bf16_f32 %0, %1, %2" : "=v"(r.u[3]) : "v"(b[2]), "v"(b[3]));
    return r.v;
}

// ---------------------------------------------------------------------------
// fused prep: Wqkv^T, Wproj^T (bf16) + conv weight expansion
// blocks [0,384): wqT; [384,512): wpT; [512,610): w7/cbx
// ---------------------------------------------------------------------------
__global__ __launch_bounds__(256) void prep_all_kernel(
    const float* __restrict__ Wqkv, const float* __restrict__ Wproj,
    const float* __restrict__ ck3, const float* __restrict__ cb3,
    const float* __restrict__ ck5, const float* __restrict__ cb5,
    const float* __restrict__ ck7, const float* __restrict__ cb7,
    u16* __restrict__ wqT, u16* __restrict__ wpT,
    float* __restrict__ w7, float* __restrict__ cbx)
{
    int blk = blockIdx.x;
    int tid = threadIdx.x;
    if (blk < 512) {
        const float* W = (blk < 384) ? Wqkv : Wproj;
        u16* Wt = (blk < 384) ? wqT : wpT;
        int N = (blk < 384) ? 1536 : 512;
        int t = (blk < 384 ? blk : blk - 384) * 256 + tid;
        int n = t >> 6;
        int k0 = (t & 63) * 8;
        u16x8 o;
#pragma unroll
        for (int j = 0; j < 8; j++) o[j] = f2bf(W[(size_t)(k0 + j) * N + n]);
        *(u16x8*)&Wt[(size_t)n * KK + k0] = o;
    } else {
        int t = (blk - 512) * 256 + tid;
        if (t >= 49 * 512) return;
        int c = t & 511;
        int tap = t >> 9;
        int dy = tap / 7, dx = tap % 7;
        float w = 0.f;
        if (c < 128) {
            int ry = dy - 2, rx = dx - 2;
            if (ry >= 0 && ry < 3 && rx >= 0 && rx < 3) w = ck3[(ry * 3 + rx) * 128 + c];
        } else if (c < 320) {
            int ry = dy - 1, rx = dx - 1;
            if (ry >= 0 && ry < 5 && rx >= 0 && rx < 5) w = ck5[(ry * 5 + rx) * 192 + (c - 128)];
        } else {
            w = ck7[(dy * 7 + dx) * 192 + (c - 320)];
        }
        w7[tap * 512 + c] = w;
        if (t < 512)
            cbx[t] = (t < 128) ? cb3[t] : (t < 320) ? cb5[t - 128] : cb7[t - 320];
    }
}

// ---------------------------------------------------------------------------
// qkv GEMM with fused fp32->bf16 A conversion (T14 reg-staged A, gload_lds B)
// A = x fp32 [MM][512] (rows clamped to MM-1 for pad tiles);
// scatters bf16 into contiguous q/k/v planes [MP][512].
// 2-phase 128x128, BK=32, identical LDS layout / frag path as proven kernel.
// ---------------------------------------------------------------------------
template <int GX>
__global__ __launch_bounds__(256) void gemm_qkv_kernel(
    const float* __restrict__ X, const u16* __restrict__ Bt,
    const float* __restrict__ bias, u16* __restrict__ qkv, int nwg)
{
    __shared__ __align__(16) u16 lds[2][2][4096];

    int wg = blockIdx.x;
    {
        int q = nwg >> 3, r = nwg & 7;
        int xcd = wg & 7, pos = wg >> 3;
        wg = (xcd < r ? xcd * (q + 1) : r * (q + 1) + (xcd - r) * q) + pos;
    }
    const int m0 = (wg / GX) * 128;
    const int n0 = (wg % GX) * 128;

    const int t = threadIdx.x;

    const int srow = t >> 2;
    const int ps   = t & 3;
    const int ls   = ps ^ ((srow >> 1) & 3);
    int ar0 = m0 + srow;      if (ar0 >= MM) ar0 = MM - 1;   // clamp pad rows
    int ar1 = m0 + 64 + srow; if (ar1 >= MM) ar1 = MM - 1;
    const float* gA0 = X + (size_t)ar0 * KK + ls * 8;
    const float* gA1 = X + (size_t)ar1 * KK + ls * 8;
    const u16* gB = Bt + (size_t)(n0 + srow) * KK + ls * 8;

    const int l  = t & 63;
    const int w  = t >> 6;
    const int wm = (w >> 1) * 64;
    const int wn = (w & 1) * 64;
    const int lr = l & 15;
    const int s  = l >> 4;
    const int ra = wm + lr;
    const int rb = wn + lr;
    const int offA = ra * 32 + (s ^ ((ra >> 1) & 3)) * 8;
    const int offB = rb * 32 + (s ^ ((rb >> 1) & 3)) * 8;

    f32x4 acc[4][4] = {};

    // prologue: buf0
    {
        f32x4 p00 = *(const f32x4*)&gA0[0], p01 = *(const f32x4*)&gA0[4];
        f32x4 p10 = *(const f32x4*)&gA1[0], p11 = *(const f32x4*)&gA1[4];
        gload16(gB, &lds[0][1][t * 8]);
        gload16(gB + 64 * KK, &lds[0][1][2048 + t * 8]);
        *(u16x8*)&lds[0][0][t * 8] = cvt8(p00, p01);
        *(u16x8*)&lds[0][0][2048 + t * 8] = cvt8(p10, p11);
    }
    __syncthreads();

    int cur = 0;
    for (int step = 0; step < 16; ++step) {
        int nxt = cur ^ 1;
        f32x4 p00, p01, p10, p11;
        if (step < 15) {
            int kn = (step + 1) * 32;
            p00 = *(const f32x4*)&gA0[kn];     p01 = *(const f32x4*)&gA0[kn + 4];
            p10 = *(const f32x4*)&gA1[kn];     p11 = *(const f32x4*)&gA1[kn + 4];
            gload16(gB + kn, &lds[nxt][1][t * 8]);
            gload16(gB + 64 * KK + kn, &lds[nxt][1][2048 + t * 8]);
        }
        bf16x8 a[4], b[4];
#pragma unroll
        for (int i = 0; i < 4; i++) a[i] = *(const bf16x8*)&lds[cur][0][offA + i * 512];
#pragma unroll
        for (int i = 0; i < 4; i++) b[i] = *(const bf16x8*)&lds[cur][1][offB + i * 512];
#pragma unroll
        for (int i = 0; i < 4; i++)
#pragma unroll
            for (int j = 0; j < 4; j++)
                acc[i][j] = __builtin_amdgcn_mfma_f32_16x16x32_bf16(a[i], b[j], acc[i][j], 0, 0, 0);
        if (step < 15) {   // convert + LDS-write after MFMA (loads hidden under it)
            *(u16x8*)&lds[nxt][0][t * 8] = cvt8(p00, p01);
            *(u16x8*)&lds[nxt][0][2048 + t * 8] = cvt8(p10, p11);
        }
        __syncthreads();
        cur = nxt;
    }

    const int row0 = m0 + wm + (l >> 4) * 4;
    const int col0 = n0 + wn + lr;
    float bs[4];
#pragma unroll
    for (int j = 0; j < 4; j++) bs[j] = bias[col0 + j * 16];

    const int plane = n0 >> 9;
    u16* pl = qkv + (size_t)plane * ((size_t)MP * CC);
#pragma unroll
    for (int i = 0; i < 4; i++) {
#pragma unroll
        for (int j = 0; j < 4; j++) {
            int gc = (col0 + j * 16) & 511;
#pragma unroll
            for (int r = 0; r < 4; r++) {
                int gm = row0 + i * 16 + r;
                pl[(size_t)gm * CC + gc] = f2bf(acc[i][j][r] + bs[j]);
            }
        }
    }
}

// ---------------------------------------------------------------------------
// proj GEMM (2-phase 128x128, bf16 A via gload_lds, fp32 out, XCD swizzle)
// ---------------------------------------------------------------------------
template <int NSZ, int GX>
__global__ __launch_bounds__(256) void gemm_proj_kernel(
    const u16* __restrict__ A, const u16* __restrict__ Bt,
    const float* __restrict__ bias, float* __restrict__ out, int nwg)
{
    __shared__ __align__(16) u16 lds[2][2][4096];

    int wg = blockIdx.x;
    {
        int q = nwg >> 3, r = nwg & 7;
        int xcd = wg & 7, pos = wg >> 3;
        wg = (xcd < r ? xcd * (q + 1) : r * (q + 1) + (xcd - r) * q) + pos;
    }
    const int m0 = (wg / GX) * 128;
    const int n0 = (wg % GX) * 128;

    const int t = threadIdx.x;

    const int srow = t >> 2;
    const int ps   = t & 3;
    const int ls   = ps ^ ((srow >> 1) & 3);
    const u16* gA = A  + (size_t)(m0 + srow) * KK + ls * 8;
    const u16* gB = Bt + (size_t)(n0 + srow) * KK + ls * 8;

    const int l  = t & 63;
    const int w  = t >> 6;
    const int wm = (w >> 1) * 64;
    const int wn = (w & 1) * 64;
    const int lr = l & 15;
    const int s  = l >> 4;
    const int ra = wm + lr;
    const int rb = wn + lr;
    const int offA = ra * 32 + (s ^ ((ra >> 1) & 3)) * 8;
    const int offB = rb * 32 + (s ^ ((rb >> 1) & 3)) * 8;

    f32x4 acc[4][4] = {};

#define STAGE(buf, kk_) do {                                        \
        gload16(gA + (kk_),           &lds[buf][0][t * 8]);         \
        gload16(gA + 64 * KK + (kk_), &lds[buf][0][2048 + t * 8]);  \
        gload16(gB + (kk_),           &lds[buf][1][t * 8]);         \
        gload16(gB + 64 * KK + (kk_), &lds[buf][1][2048 + t * 8]);  \
    } while (0)

    STAGE(0, 0);
    __syncthreads();

    int cur = 0;
    for (int step = 0; step < 16; ++step) {
        if (step < 15) STAGE(cur ^ 1, (step + 1) * 32);
        bf16x8 a[4], b[4];
#pragma unroll
        for (int i = 0; i < 4; i++) a[i] = *(const bf16x8*)&lds[cur][0][offA + i * 512];
#pragma unroll
        for (int i = 0; i < 4; i++) b[i] = *(const bf16x8*)&lds[cur][1][offB + i * 512];
#pragma unroll
        for (int i = 0; i < 4; i++)
#pragma unroll
            for (int j = 0; j < 4; j++)
                acc[i][j] = __builtin_amdgcn_mfma_f32_16x16x32_bf16(a[i], b[j], acc[i][j], 0, 0, 0);
        __syncthreads();
        cur ^= 1;
    }
#undef STAGE

    const int row0 = m0 + wm + (l >> 4) * 4;
    const int col0 = n0 + wn + lr;
    float bs[4];
#pragma unroll
    for (int j = 0; j < 4; j++) bs[j] = bias[col0 + j * 16];

#pragma unroll
    for (int i = 0; i < 4; i++) {
#pragma unroll
        for (int j = 0; j < 4; j++) {
            int gn = col0 + j * 16;
#pragma unroll
            for (int r = 0; r < 4; r++) {
                int gm = row0 + i * 16 + r;
                if (gm < MM) out[(size_t)gm * NSZ + gn] = acc[i][j][r] + bs[j];
            }
        }
    }
}

// ---------------------------------------------------------------------------
// ksv partials (no max subtraction; k ~ O(1) so exp(k) is f32-safe):
// part[chunk][bh][kk][vv] = sum_{n in chunk} exp(k) * v ; psum = sum exp(k)
// ---------------------------------------------------------------------------
__global__ __launch_bounds__(256) void ksv_part_kernel(
    const u16* __restrict__ kbf, const u16* __restrict__ vbf,
    float* __restrict__ part, float* __restrict__ psum)
{
    int bh = blockIdx.x;
    int chunk = blockIdx.y;
    int b = bh >> 3, h = bh & 7;
    int n0 = chunk * 256;
    int n1 = (chunk == 3) ? NN : n0 + 256;

    __shared__ float ke[16][64];
    __shared__ float ve[16][64];

    int t = threadIdx.x;
    int lrow = t >> 4;
    int lcol = (t & 15) * 4;
    int tx = t & 15, ty = t >> 4;

    float acc[4][4] = {};
    float cs[4] = {};
    for (int nb = n0; nb < n1; nb += 16) {
        int n = nb + lrow;
        bool valid = n < n1;
        size_t off = ((size_t)(b * NN + n)) * CC + h * HD + lcol;  // padded plane
        u16x4 kr = *(const u16x4*)&kbf[off];
        u16x4 vr = *(const u16x4*)&vbf[off];
#pragma unroll
        for (int j = 0; j < 4; j++) {
            ke[lrow][lcol + j] = valid ? __expf(bf2f(kr[j])) : 0.f;
            ve[lrow][lcol + j] = valid ? bf2f(vr[j]) : 0.f;
        }
        __syncthreads();
#pragma unroll 4
        for (int d = 0; d < 16; d++) {
            f32x4 ka = *(const f32x4*)&ke[d][ty * 4];
            f32x4 vb = *(const f32x4*)&ve[d][tx * 4];
#pragma unroll
            for (int i = 0; i < 4; i++)
#pragma unroll
                for (int j = 0; j < 4; j++)
                    acc[i][j] = fmaf(ka[i], vb[j], acc[i][j]);
        }
        if (t < 16) {
#pragma unroll
            for (int d = 0; d < 16; d++) {
                f32x4 kv = *(const f32x4*)&ke[d][t * 4];
#pragma unroll
                for (int j = 0; j < 4; j++) cs[j] += kv[j];
            }
        }
        __syncthreads();
    }

    float* dst = part + ((size_t)chunk * 256 + bh) * 4096;
#pragma unroll
    for (int i = 0; i < 4; i++) {
        f32x4 o = {acc[i][0], acc[i][1], acc[i][2], acc[i][3]};
        *(f32x4*)&dst[(ty * 4 + i) * 64 + tx * 4] = o;
    }
    if (t < 16) {
        f32x4 o = {cs[0], cs[1], cs[2], cs[3]};
        *(f32x4*)&psum[((size_t)chunk * 256 + bh) * 64 + t * 4] = o;
    }
}

// ---------------------------------------------------------------------------
// ksvT[bh][vv][kk] = bf16( SCALE * (sum_c part[c][bh][kk][vv]) / sum_c psum )
// ---------------------------------------------------------------------------
__global__ __launch_bounds__(256) void ksv_reduceT_kernel(
    const float* __restrict__ part, const float* __restrict__ psum,
    u16* __restrict__ ksvT)
{
    int i = blockIdx.x * 256 + threadIdx.x;   // f32x4 units
    size_t e = (size_t)i * 4;
    int bh = (int)(e >> 12);
    int kk = ((int)e >> 6) & 63;
    int vv0 = (int)e & 63;
    f32x4 s = *(const f32x4*)&part[e];
    float cs = psum[bh * 64 + kk];
#pragma unroll
    for (int c = 1; c < 4; c++) {
        f32x4 p = *(const f32x4*)&part[(size_t)c * 256 * 4096 + e];
#pragma unroll
        for (int j = 0; j < 4; j++) s[j] += p[j];
        cs += psum[(size_t)c * 256 * 64 + bh * 64 + kk];
    }
    float inv = SCALE / cs;
#pragma unroll
    for (int j = 0; j < 4; j++)
        ksvT[(size_t)bh * 4096 + (vv0 + j) * 64 + kk] = f2bf(s[j] * inv);
}

// ---------------------------------------------------------------------------
// FUSED attn+ev (+n=0 GEMV at yg==8):
//   att = bf16( q @ ksvT^T ) + q ⊙ (dwconv(v) + cb)      [write-only]
// ---------------------------------------------------------------------------
__global__ __launch_bounds__(256) void attn_ev_kernel(
    const u16* __restrict__ qbf, const u16* __restrict__ vbf,
    const u16* __restrict__ ksvT, const float* __restrict__ w7,
    const float* __restrict__ cbx, u16* __restrict__ attbf)
{
    int yg = blockIdx.x;            // 0..8 (8 = n=0 GEMV)
    int bh = blockIdx.y;
    int b = bh >> 3, h = bh & 7;
    int t = threadIdx.x;

    if (yg == 8) {                  // n=0 row for this (b,h): 64 outputs
        if (t < 64) {
            const u16* q0 = qbf + (size_t)(b * NN) * CC + h * HD;
            const u16* kb = ksvT + (size_t)bh * 4096 + t * 64;
            float s = 0.f;
#pragma unroll 8
            for (int kk = 0; kk < 64; kk++)
                s = fmaf(bf2f(q0[kk]), bf2f(kb[kk]), s);
            attbf[(size_t)(b * NN) * CC + h * HD + t] = f2bf(s);
        }
        return;
    }

    const int nbase = 1 + yg * 128;

    __shared__ __align__(16) u16 lq[128 * 64];
    __shared__ __align__(16) u16 lk[64 * 64];
    __shared__ __align__(16) u16 lv[10 * 32 * 64];
    __shared__ __align__(16) u16 latt[128 * 64];

    // ---- stage q (swizzled), ksvT (swizzled), v halo (linear, zero-padded)
#pragma unroll
    for (int i = 0; i < 4; i++) {
        int idx = t + i * 256;
        int row = idx >> 3, sl = idx & 7;
        u16x8 v = *(const u16x8*)&qbf[((size_t)(b * NN + nbase + row)) * CC + h * HD + sl * 8];
        *(u16x8*)&lq[row * 64 + ((sl ^ (row & 7)) * 8)] = v;
    }
#pragma unroll
    for (int i = 0; i < 2; i++) {
        int idx = t + i * 256;
        int col = idx >> 3, sl = idx & 7;
        u16x8 v = *(const u16x8*)&ksvT[(size_t)bh * 4096 + col * 64 + sl * 8];
        *(u16x8*)&lk[col * 64 + ((col & 7) ^ sl) * 8] = v;
    }
    {
        int x = t >> 3, sl = t & 7;
#pragma unroll
        for (int s = 0; s < 10; s++) {
            int yy = yg * 4 - 3 + s;
            u16x8 v;
            if (yy >= 0 && yy < 32)
                v = *(const u16x8*)&vbf[((size_t)(b * NN) + 1 + yy * 32 + x) * CC + h * HD + sl * 8];
            else {
#pragma unroll
                for (int j = 0; j < 8; j++) v[j] = 0;
            }
            *(u16x8*)&lv[s * 2048 + x * 64 + sl * 8] = v;
        }
    }
    __syncthreads();

    // ---- factor term via MFMA (4 waves x 32 rows)
    {
        int l = t & 63, w = t >> 6;
        int lr = l & 15, ls = l >> 4;
        f32x4 acc[2][4] = {};
#pragma unroll
        for (int kf = 0; kf < 2; kf++) {
            bf16x8 a[2], bf[4];
#pragma unroll
            for (int i = 0; i < 2; i++) {
                int row = w * 32 + i * 16 + lr;
                a[i] = *(const bf16x8*)&lq[row * 64 + (((kf * 4 + ls) ^ (row & 7)) * 8)];
            }
#pragma unroll
            for (int j = 0; j < 4; j++) {
                int col = j * 16 + lr;
                bf[j] = *(const bf16x8*)&lk[col * 64 + (((kf * 4 + ls) ^ (col & 7)) * 8)];
            }
#pragma unroll
            for (int i = 0; i < 2; i++)
#pragma unroll
                for (int j = 0; j < 4; j++)
                    acc[i][j] = __builtin_amdgcn_mfma_f32_16x16x32_bf16(a[i], bf[j], acc[i][j], 0, 0, 0);
        }
#pragma unroll
        for (int i = 0; i < 2; i++)
#pragma unroll
            for (int j = 0; j < 4; j++)
#pragma unroll
                for (int r = 0; r < 4; r++)
                    latt[(w * 32 + i * 16 + ls * 4 + r) * 64 + j * 16 + lr] =
                        f2bf(acc[i][j][r]);
    }
    __syncthreads();

    // ---- conv phase: thread = 8 px (x-run) x 4 ch
    int oct = t >> 4;
    int cq = t & 15;
    int c4 = cq * 4;
    int c = h * HD + c4;
    int yo = oct >> 2;
    int x0 = (oct & 3) * 8;

    float a2[8][4];
    {
        f32x4 b0 = *(const f32x4*)&cbx[c];
#pragma unroll
        for (int xi = 0; xi < 8; xi++)
#pragma unroll
            for (int j = 0; j < 4; j++) a2[xi][j] = b0[j];
    }

    for (int dy = 0; dy < 7; dy++) {
        int s = yo + dy;
        float wr[7][4];
#pragma unroll
        for (int dx = 0; dx < 7; dx++)
            *(f32x4*)&wr[dx][0] = *(const f32x4*)&w7[(dy * 7 + dx) * 512 + c];
        u16x4 vv[14];
#pragma unroll
        for (int sxi = 0; sxi < 14; sxi++) {
            int sx = x0 - 3 + sxi;
            int sxc = sx < 0 ? 0 : (sx > 31 ? 31 : sx);
            vv[sxi] = *(const u16x4*)&lv[s * 2048 + sxc * 64 + c4];
        }
#pragma unroll
        for (int sxi = 0; sxi < 14; sxi++) {
            int sx = x0 - 3 + sxi;
            bool xval = (sx >= 0) && (sx < 32);
            float vf[4];
#pragma unroll
            for (int j = 0; j < 4; j++) vf[j] = xval ? bf2f(vv[sxi][j]) : 0.f;
            int lo = sxi - 6 > 0 ? sxi - 6 : 0;
            int hi = sxi < 7 ? sxi : 7;
#pragma unroll
            for (int xi = 0; xi < 8; xi++) {
                if (xi < lo || xi > hi) continue;
                int dx = sxi - xi;
#pragma unroll
                for (int j = 0; j < 4; j++)
                    a2[xi][j] = fmaf(vf[j], wr[dx][j], a2[xi][j]);
            }
        }
    }

    // ---- combine factor (latt) + q*ev and store
#pragma unroll
    for (int xi = 0; xi < 8; xi++) {
        int row = oct * 8 + xi;
        u16x4 at = *(const u16x4*)&latt[row * 64 + c4];
        u16x4 qv = *(const u16x4*)&lq[row * 64 + (((cq >> 1) ^ (row & 7)) * 8) + (cq & 1) * 4];
        u16x4 ov;
#pragma unroll
        for (int j = 0; j < 4; j++)
            ov[j] = f2bf(bf2f(at[j]) + bf2f(qv[j]) * a2[xi][j]);
        *(u16x4*)&attbf[((size_t)(b * NN + nbase + row)) * CC + c] = ov;
    }
}

// ---------------------------------------------------------------------------
extern "C" void kernel_launch(void* const* d_in, const int* in_sizes, int n_in,
                              void* d_out, int out_size, void* d_ws, size_t ws_size,
                              hipStream_t stream)
{
    const float* x     = (const float*)d_in[0];
    const float* Wqkv  = (const float*)d_in[1];
    const float* bqkv  = (const float*)d_in[2];
    const float* Wproj = (const float*)d_in[3];
    const float* bproj = (const float*)d_in[4];
    const float* ck3   = (const float*)d_in[5];
    const float* cb3   = (const float*)d_in[6];
    const float* ck5   = (const float*)d_in[7];
    const float* cb5   = (const float*)d_in[8];
    const float* ck7   = (const float*)d_in[9];
    const float* cb7   = (const float*)d_in[10];
    float* out = (float*)d_out;

    const size_t PLANE = (size_t)MP * CC;

    u16* qbf   = (u16*)d_ws;                       // q/k/v planes contiguous
    u16* kbf   = qbf + PLANE;
    u16* vbf   = kbf + PLANE;
    u16* attbf = vbf + PLANE;                      // own plane (no aliasing)
    u16* wqT   = attbf + PLANE;
    u16* wpT   = wqT + (size_t)1536 * 512;
    u16* ksvT  = wpT + (size_t)512 * 512;          // 256*4096 bf16
    float* psum = (float*)(ksvT + (size_t)256 * 4096);  // 4*256*64
    float* part = psum + (size_t)4 * 256 * 64;     // 4*256*4096 f32
    float* w7   = part + (size_t)4 * 256 * 4096;   // 49*512
    float* cbx  = w7 + 49 * 512;                   // 512

    // 1) fused prep (weight transposes + conv expansion)
    prep_all_kernel<<<610, 256, 0, stream>>>(
        Wqkv, Wproj, ck3, cb3, ck5, cb5, ck7, cb7, wqT, wpT, w7, cbx);

    // 2) qkv GEMM with fused fp32->bf16 A conversion -> q/k/v planes
    {
        int nwg = 12 * (MP / 128);   // 3096
        gemm_qkv_kernel<12><<<nwg, 256, 0, stream>>>(x, wqT, bqkv, qbf, nwg);
    }
    // 3) ksv partials (no-max, fused colsum) + transpose-reduce -> bf16 ksvT
    {
        dim3 grid(BB * HH, 4);
        ksv_part_kernel<<<grid, 256, 0, stream>>>(kbf, vbf, part, psum);
        ksv_reduceT_kernel<<<256 * 4096 / 4 / 256, 256, 0, stream>>>(part, psum, ksvT);
    }
    // 4) fused factor+conv+n0 -> attbf
    {
        dim3 grid(9, BB * HH);
        attn_ev_kernel<<<grid, 256, 0, stream>>>(qbf, vbf, ksvT, w7, cbx, attbf);
    }
    // 5) proj GEMM -> out
    {
        int nwg = 4 * (MP / 128);    // 1032
        gemm_proj_kernel<512, 4><<<nwg, 256, 0, stream>>>(attbf, wpT, bproj, out, nwg);
    }
}

// Round 11
// 231.364 us; speedup vs baseline: 1.0938x; 1.0938x over previous
//
#include <hip/hip_runtime.h>
#include <hip/hip_bf16.h>

#define BB 32
#define NN 1025
#define CC 512
#define HH 8
#define HD 64
#define MM (BB * NN)        // 32800
#define MP 33024            // padded plane rows (258 * 128)
#define KK 512
#define SCALE 0.125f

typedef unsigned short u16;
typedef __attribute__((ext_vector_type(4))) unsigned short u16x4;
typedef __attribute__((ext_vector_type(8))) unsigned short u16x8;
typedef __attribute__((ext_vector_type(4))) float f32x4;
typedef __attribute__((ext_vector_type(8))) __bf16 bf16x8;

__device__ __forceinline__ u16 f2bf(float f) {
    unsigned u = __float_as_uint(f);
    unsigned r = (u + 0x7FFFu + ((u >> 16) & 1u)) >> 16;
    return (u16)r;
}
__device__ __forceinline__ float bf2f(u16 h) {
    return __uint_as_float((unsigned)h << 16);
}

__device__ __forceinline__ void gload16(const u16* g, u16* l) {
    __builtin_amdgcn_global_load_lds(
        (const __attribute__((address_space(1))) unsigned int*)g,
        (__attribute__((address_space(3))) unsigned int*)l, 16, 0, 0);
}

// ---------------------------------------------------------------------------
// convert x (fp32 [MM][512]) -> xbf (bf16 [MP][512]), zero pad rows
// ---------------------------------------------------------------------------
__global__ __launch_bounds__(256) void convert_x_kernel(
    const float* __restrict__ x, u16* __restrict__ xbf)
{
    size_t t = (size_t)blockIdx.x * 256 + threadIdx.x;
    size_t base = t * 8;
    u16x8 o;
    if (base < (size_t)MM * CC) {
        f32x4 a = *(const f32x4*)&x[base];
        f32x4 b = *(const f32x4*)&x[base + 4];
#pragma unroll
        for (int j = 0; j < 4; j++) { o[j] = f2bf(a[j]); o[j + 4] = f2bf(b[j]); }
    } else {
#pragma unroll
        for (int j = 0; j < 8; j++) o[j] = 0;
    }
    *(u16x8*)&xbf[base] = o;
}

// ---------------------------------------------------------------------------
// fused prep: Wqkv^T, Wproj^T (bf16) + conv weight expansion
// blocks [0,384): wqT; [384,512): wpT; [512,610): w7/cbx
// ---------------------------------------------------------------------------
__global__ __launch_bounds__(256) void prep_all_kernel(
    const float* __restrict__ Wqkv, const float* __restrict__ Wproj,
    const float* __restrict__ ck3, const float* __restrict__ cb3,
    const float* __restrict__ ck5, const float* __restrict__ cb5,
    const float* __restrict__ ck7, const float* __restrict__ cb7,
    u16* __restrict__ wqT, u16* __restrict__ wpT,
    float* __restrict__ w7, float* __restrict__ cbx)
{
    int blk = blockIdx.x;
    int tid = threadIdx.x;
    if (blk < 512) {
        const float* W = (blk < 384) ? Wqkv : Wproj;
        u16* Wt = (blk < 384) ? wqT : wpT;
        int N = (blk < 384) ? 1536 : 512;
        int t = (blk < 384 ? blk : blk - 384) * 256 + tid;
        int n = t >> 6;
        int k0 = (t & 63) * 8;
        u16x8 o;
#pragma unroll
        for (int j = 0; j < 8; j++) o[j] = f2bf(W[(size_t)(k0 + j) * N + n]);
        *(u16x8*)&Wt[(size_t)n * KK + k0] = o;
    } else {
        int t = (blk - 512) * 256 + tid;
        if (t >= 49 * 512) return;
        int c = t & 511;
        int tap = t >> 9;
        int dy = tap / 7, dx = tap % 7;
        float w = 0.f;
        if (c < 128) {
            int ry = dy - 2, rx = dx - 2;
            if (ry >= 0 && ry < 3 && rx >= 0 && rx < 3) w = ck3[(ry * 3 + rx) * 128 + c];
        } else if (c < 320) {
            int ry = dy - 1, rx = dx - 1;
            if (ry >= 0 && ry < 5 && rx >= 0 && rx < 5) w = ck5[(ry * 5 + rx) * 192 + (c - 128)];
        } else {
            w = ck7[(dy * 7 + dx) * 192 + (c - 320)];
        }
        w7[tap * 512 + c] = w;
        if (t < 512)
            cbx[t] = (t < 128) ? cb3[t] : (t < 320) ? cb5[t - 128] : cb7[t - 320];
    }
}

// ---------------------------------------------------------------------------
// bf16 MFMA GEMM (2-phase 128x128, BK=32) + XCD-bijective 1D swizzle.
// MODE 0: bf16 scatter to q/k/v planes via LDS-coalesced epilogue.
// MODE 1: fp32 output, direct stores.
// ---------------------------------------------------------------------------
template <int MODE, int NSZ, int GX>
__global__ __launch_bounds__(256) void gemm_bf16_kernel(
    const u16* __restrict__ A, const u16* __restrict__ Bt,
    const float* __restrict__ bias, void* __restrict__ outv, int nwg)
{
    __shared__ __align__(16) u16 lds[2][2][4096];

    int wg = blockIdx.x;
    {
        int q = nwg >> 3, r = nwg & 7;
        int xcd = wg & 7, pos = wg >> 3;
        wg = (xcd < r ? xcd * (q + 1) : r * (q + 1) + (xcd - r) * q) + pos;
    }
    const int m0 = (wg / GX) * 128;
    const int n0 = (wg % GX) * 128;

    const int t = threadIdx.x;

    const int srow = t >> 2;
    const int ps   = t & 3;
    const int ls   = ps ^ ((srow >> 1) & 3);
    const u16* gA = A  + (size_t)(m0 + srow) * KK + ls * 8;
    const u16* gB = Bt + (size_t)(n0 + srow) * KK + ls * 8;

    const int l  = t & 63;
    const int w  = t >> 6;
    const int wm = (w >> 1) * 64;
    const int wn = (w & 1) * 64;
    const int lr = l & 15;
    const int s  = l >> 4;
    const int ra = wm + lr;
    const int rb = wn + lr;
    const int offA = ra * 32 + (s ^ ((ra >> 1) & 3)) * 8;
    const int offB = rb * 32 + (s ^ ((rb >> 1) & 3)) * 8;

    f32x4 acc[4][4] = {};

#define STAGE(buf, kk_) do {                                        \
        gload16(gA + (kk_),           &lds[buf][0][t * 8]);         \
        gload16(gA + 64 * KK + (kk_), &lds[buf][0][2048 + t * 8]);  \
        gload16(gB + (kk_),           &lds[buf][1][t * 8]);         \
        gload16(gB + 64 * KK + (kk_), &lds[buf][1][2048 + t * 8]);  \
    } while (0)

    STAGE(0, 0);
    __syncthreads();

    int cur = 0;
    for (int step = 0; step < 16; ++step) {
        if (step < 15) STAGE(cur ^ 1, (step + 1) * 32);
        bf16x8 a[4], b[4];
#pragma unroll
        for (int i = 0; i < 4; i++) a[i] = *(const bf16x8*)&lds[cur][0][offA + i * 512];
#pragma unroll
        for (int i = 0; i < 4; i++) b[i] = *(const bf16x8*)&lds[cur][1][offB + i * 512];
#pragma unroll
        for (int i = 0; i < 4; i++)
#pragma unroll
            for (int j = 0; j < 4; j++)
                acc[i][j] = __builtin_amdgcn_mfma_f32_16x16x32_bf16(a[i], b[j], acc[i][j], 0, 0, 0);
        __syncthreads();
        cur ^= 1;
    }
#undef STAGE

    const int col0 = n0 + wn + lr;
    float bs[4];
#pragma unroll
    for (int j = 0; j < 4; j++) bs[j] = bias[col0 + j * 16];

    if (MODE == 0) {
        // ---- coalesced epilogue: acc -> LDS (u16, bank-spread XOR) -> 16B stores
        u16* eb = &lds[0][0][0];                  // 32 KB = [128][128] u16
        const int rl0 = wm + (l >> 4) * 4;
        const int cl0 = wn + lr;
#pragma unroll
        for (int i = 0; i < 4; i++) {
#pragma unroll
            for (int j = 0; j < 4; j++) {
#pragma unroll
                for (int r = 0; r < 4; r++) {
                    int row = rl0 + i * 16 + r;
                    int a_ = (row * 256 + (cl0 + j * 16) * 2) ^ ((row & 12) << 3);
                    eb[a_ >> 1] = f2bf(acc[i][j][r] + bs[j]);
                }
            }
        }
        __syncthreads();
        const int plane = n0 >> 9;
        u16* pl = (u16*)outv + (size_t)plane * ((size_t)MP * CC) + (n0 & 511);
#pragma unroll
        for (int s2 = 0; s2 < 8; s2++) {
            int flat = s2 * 2048 + t * 8;
            int row = flat >> 7, col = flat & 127;
            int a_ = (row * 256 + col * 2) ^ ((row & 12) << 3);
            u16x8 v = *(const u16x8*)((const char*)eb + a_);
            *(u16x8*)&pl[(size_t)(m0 + row) * CC + col] = v;
        }
    } else {
        float* out = (float*)outv;
        const int row0 = m0 + wm + (l >> 4) * 4;
#pragma unroll
        for (int i = 0; i < 4; i++) {
#pragma unroll
            for (int j = 0; j < 4; j++) {
                int gn = col0 + j * 16;
#pragma unroll
                for (int r = 0; r < 4; r++) {
                    int gm = row0 + i * 16 + r;
                    if (gm < MM) out[(size_t)gm * NSZ + gn] = acc[i][j][r] + bs[j];
                }
            }
        }
    }
}

// ---------------------------------------------------------------------------
// ksv partials (no max subtraction; k ~ O(1) so exp(k) is f32-safe):
// part[chunk][bh][kk][vv] = sum_{n in chunk} exp(k) * v ; psum = sum exp(k)
// ---------------------------------------------------------------------------
__global__ __launch_bounds__(256) void ksv_part_kernel(
    const u16* __restrict__ kbf, const u16* __restrict__ vbf,
    float* __restrict__ part, float* __restrict__ psum)
{
    int bh = blockIdx.x;
    int chunk = blockIdx.y;
    int b = bh >> 3, h = bh & 7;
    int n0 = chunk * 256;
    int n1 = (chunk == 3) ? NN : n0 + 256;

    __shared__ float ke[16][64];
    __shared__ float ve[16][64];

    int t = threadIdx.x;
    int lrow = t >> 4;
    int lcol = (t & 15) * 4;
    int tx = t & 15, ty = t >> 4;

    float acc[4][4] = {};
    float cs[4] = {};
    for (int nb = n0; nb < n1; nb += 16) {
        int n = nb + lrow;
        bool valid = n < n1;
        size_t off = ((size_t)(b * NN + n)) * CC + h * HD + lcol;  // padded plane
        u16x4 kr = *(const u16x4*)&kbf[off];
        u16x4 vr = *(const u16x4*)&vbf[off];
#pragma unroll
        for (int j = 0; j < 4; j++) {
            ke[lrow][lcol + j] = valid ? __expf(bf2f(kr[j])) : 0.f;
            ve[lrow][lcol + j] = valid ? bf2f(vr[j]) : 0.f;
        }
        __syncthreads();
#pragma unroll 4
        for (int d = 0; d < 16; d++) {
            f32x4 ka = *(const f32x4*)&ke[d][ty * 4];
            f32x4 vb = *(const f32x4*)&ve[d][tx * 4];
#pragma unroll
            for (int i = 0; i < 4; i++)
#pragma unroll
                for (int j = 0; j < 4; j++)
                    acc[i][j] = fmaf(ka[i], vb[j], acc[i][j]);
        }
        if (t < 16) {
#pragma unroll
            for (int d = 0; d < 16; d++) {
                f32x4 kv = *(const f32x4*)&ke[d][t * 4];
#pragma unroll
                for (int j = 0; j < 4; j++) cs[j] += kv[j];
            }
        }
        __syncthreads();
    }

    float* dst = part + ((size_t)chunk * 256 + bh) * 4096;
#pragma unroll
    for (int i = 0; i < 4; i++) {
        f32x4 o = {acc[i][0], acc[i][1], acc[i][2], acc[i][3]};
        *(f32x4*)&dst[(ty * 4 + i) * 64 + tx * 4] = o;
    }
    if (t < 16) {
        f32x4 o = {cs[0], cs[1], cs[2], cs[3]};
        *(f32x4*)&psum[((size_t)chunk * 256 + bh) * 64 + t * 4] = o;
    }
}

// ---------------------------------------------------------------------------
// ksvT[bh][vv][kk] = bf16( SCALE * (sum_c part[c][bh][kk][vv]) / sum_c psum )
// ---------------------------------------------------------------------------
__global__ __launch_bounds__(256) void ksv_reduceT_kernel(
    const float* __restrict__ part, const float* __restrict__ psum,
    u16* __restrict__ ksvT)
{
    int i = blockIdx.x * 256 + threadIdx.x;   // f32x4 units
    size_t e = (size_t)i * 4;
    int bh = (int)(e >> 12);
    int kk = ((int)e >> 6) & 63;
    int vv0 = (int)e & 63;
    f32x4 s = *(const f32x4*)&part[e];
    float cs = psum[bh * 64 + kk];
#pragma unroll
    for (int c = 1; c < 4; c++) {
        f32x4 p = *(const f32x4*)&part[(size_t)c * 256 * 4096 + e];
#pragma unroll
        for (int j = 0; j < 4; j++) s[j] += p[j];
        cs += psum[(size_t)c * 256 * 64 + bh * 64 + kk];
    }
    float inv = SCALE / cs;
#pragma unroll
    for (int j = 0; j < 4; j++)
        ksvT[(size_t)bh * 4096 + (vv0 + j) * 64 + kk] = f2bf(s[j] * inv);
}

// ---------------------------------------------------------------------------
// FUSED attn+ev (+n=0 GEMV at yg==8):
//   att = bf16( q @ ksvT^T ) + q ⊙ (dwconv(v) + cb)      [write-only]
// ---------------------------------------------------------------------------
__global__ __launch_bounds__(256) void attn_ev_kernel(
    const u16* __restrict__ qbf, const u16* __restrict__ vbf,
    const u16* __restrict__ ksvT, const float* __restrict__ w7,
    const float* __restrict__ cbx, u16* __restrict__ attbf)
{
    int yg = blockIdx.x;            // 0..8 (8 = n=0 GEMV)
    int bh = blockIdx.y;
    int b = bh >> 3, h = bh & 7;
    int t = threadIdx.x;

    if (yg == 8) {                  // n=0 row for this (b,h): 64 outputs
        if (t < 64) {
            const u16* q0 = qbf + (size_t)(b * NN) * CC + h * HD;
            const u16* kb = ksvT + (size_t)bh * 4096 + t * 64;
            float s = 0.f;
#pragma unroll 8
            for (int kk = 0; kk < 64; kk++)
                s = fmaf(bf2f(q0[kk]), bf2f(kb[kk]), s);
            attbf[(size_t)(b * NN) * CC + h * HD + t] = f2bf(s);
        }
        return;
    }

    const int nbase = 1 + yg * 128;

    __shared__ __align__(16) u16 lq[128 * 64];
    __shared__ __align__(16) u16 lk[64 * 64];
    __shared__ __align__(16) u16 lv[10 * 32 * 64];
    __shared__ __align__(16) u16 latt[128 * 64];

    // ---- stage q (swizzled), ksvT (swizzled), v halo (linear, zero-padded)
#pragma unroll
    for (int i = 0; i < 4; i++) {
        int idx = t + i * 256;
        int row = idx >> 3, sl = idx & 7;
        u16x8 v = *(const u16x8*)&qbf[((size_t)(b * NN + nbase + row)) * CC + h * HD + sl * 8];
        *(u16x8*)&lq[row * 64 + ((sl ^ (row & 7)) * 8)] = v;
    }
#pragma unroll
    for (int i = 0; i < 2; i++) {
        int idx = t + i * 256;
        int col = idx >> 3, sl = idx & 7;
        u16x8 v = *(const u16x8*)&ksvT[(size_t)bh * 4096 + col * 64 + sl * 8];
        *(u16x8*)&lk[col * 64 + ((col & 7) ^ sl) * 8] = v;
    }
    {
        int x = t >> 3, sl = t & 7;
#pragma unroll
        for (int s = 0; s < 10; s++) {
            int yy = yg * 4 - 3 + s;
            u16x8 v;
            if (yy >= 0 && yy < 32)
                v = *(const u16x8*)&vbf[((size_t)(b * NN) + 1 + yy * 32 + x) * CC + h * HD + sl * 8];
            else {
#pragma unroll
                for (int j = 0; j < 8; j++) v[j] = 0;
            }
            *(u16x8*)&lv[s * 2048 + x * 64 + sl * 8] = v;
        }
    }
    __syncthreads();

    // ---- factor term via MFMA (4 waves x 32 rows)
    {
        int l = t & 63, w = t >> 6;
        int lr = l & 15, ls = l >> 4;
        f32x4 acc[2][4] = {};
#pragma unroll
        for (int kf = 0; kf < 2; kf++) {
            bf16x8 a[2], bf[4];
#pragma unroll
            for (int i = 0; i < 2; i++) {
                int row = w * 32 + i * 16 + lr;
                a[i] = *(const bf16x8*)&lq[row * 64 + (((kf * 4 + ls) ^ (row & 7)) * 8)];
            }
#pragma unroll
            for (int j = 0; j < 4; j++) {
                int col = j * 16 + lr;
                bf[j] = *(const bf16x8*)&lk[col * 64 + (((kf * 4 + ls) ^ (col & 7)) * 8)];
            }
#pragma unroll
            for (int i = 0; i < 2; i++)
#pragma unroll
                for (int j = 0; j < 4; j++)
                    acc[i][j] = __builtin_amdgcn_mfma_f32_16x16x32_bf16(a[i], bf[j], acc[i][j], 0, 0, 0);
        }
#pragma unroll
        for (int i = 0; i < 2; i++)
#pragma unroll
            for (int j = 0; j < 4; j++)
#pragma unroll
                for (int r = 0; r < 4; r++)
                    latt[(w * 32 + i * 16 + ls * 4 + r) * 64 + j * 16 + lr] =
                        f2bf(acc[i][j][r]);
    }
    __syncthreads();

    // ---- conv phase: thread = 8 px (x-run) x 4 ch
    int oct = t >> 4;
    int cq = t & 15;
    int c4 = cq * 4;
    int c = h * HD + c4;
    int yo = oct >> 2;
    int x0 = (oct & 3) * 8;

    float a2[8][4];
    {
        f32x4 b0 = *(const f32x4*)&cbx[c];
#pragma unroll
        for (int xi = 0; xi < 8; xi++)
#pragma unroll
            for (int j = 0; j < 4; j++) a2[xi][j] = b0[j];
    }

    for (int dy = 0; dy < 7; dy++) {
        int s = yo + dy;
        float wr[7][4];
#pragma unroll
        for (int dx = 0; dx < 7; dx++)
            *(f32x4*)&wr[dx][0] = *(const f32x4*)&w7[(dy * 7 + dx) * 512 + c];
        u16x4 vv[14];
#pragma unroll
        for (int sxi = 0; sxi < 14; sxi++) {
            int sx = x0 - 3 + sxi;
            int sxc = sx < 0 ? 0 : (sx > 31 ? 31 : sx);
            vv[sxi] = *(const u16x4*)&lv[s * 2048 + sxc * 64 + c4];
        }
#pragma unroll
        for (int sxi = 0; sxi < 14; sxi++) {
            int sx = x0 - 3 + sxi;
            bool xval = (sx >= 0) && (sx < 32);
            float vf[4];
#pragma unroll
            for (int j = 0; j < 4; j++) vf[j] = xval ? bf2f(vv[sxi][j]) : 0.f;
            int lo = sxi - 6 > 0 ? sxi - 6 : 0;
            int hi = sxi < 7 ? sxi : 7;
#pragma unroll
            for (int xi = 0; xi < 8; xi++) {
                if (xi < lo || xi > hi) continue;
                int dx = sxi - xi;
#pragma unroll
                for (int j = 0; j < 4; j++)
                    a2[xi][j] = fmaf(vf[j], wr[dx][j], a2[xi][j]);
            }
        }
    }

    // ---- combine factor (latt) + q*ev and store
#pragma unroll
    for (int xi = 0; xi < 8; xi++) {
        int row = oct * 8 + xi;
        u16x4 at = *(const u16x4*)&latt[row * 64 + c4];
        u16x4 qv = *(const u16x4*)&lq[row * 64 + (((cq >> 1) ^ (row & 7)) * 8) + (cq & 1) * 4];
        u16x4 ov;
#pragma unroll
        for (int j = 0; j < 4; j++)
            ov[j] = f2bf(bf2f(at[j]) + bf2f(qv[j]) * a2[xi][j]);
        *(u16x4*)&attbf[((size_t)(b * NN + nbase + row)) * CC + c] = ov;
    }
}

// ---------------------------------------------------------------------------
extern "C" void kernel_launch(void* const* d_in, const int* in_sizes, int n_in,
                              void* d_out, int out_size, void* d_ws, size_t ws_size,
                              hipStream_t stream)
{
    const float* x     = (const float*)d_in[0];
    const float* Wqkv  = (const float*)d_in[1];
    const float* bqkv  = (const float*)d_in[2];
    const float* Wproj = (const float*)d_in[3];
    const float* bproj = (const float*)d_in[4];
    const float* ck3   = (const float*)d_in[5];
    const float* cb3   = (const float*)d_in[6];
    const float* ck5   = (const float*)d_in[7];
    const float* cb5   = (const float*)d_in[8];
    const float* ck7   = (const float*)d_in[9];
    const float* cb7   = (const float*)d_in[10];
    float* out = (float*)d_out;

    const size_t PLANE = (size_t)MP * CC;

    u16* xbf  = (u16*)d_ws;
    u16* qbf  = xbf + PLANE;
    u16* kbf  = qbf + PLANE;
    u16* vbf  = kbf + PLANE;
    u16* wqT  = vbf + PLANE;
    u16* wpT  = wqT + (size_t)1536 * 512;
    u16* ksvT = wpT + (size_t)512 * 512;           // 256*4096 bf16
    float* psum = (float*)(ksvT + (size_t)256 * 4096);  // 4*256*64
    float* part = psum + (size_t)4 * 256 * 64;     // 4*256*4096 f32
    float* w7   = part + (size_t)4 * 256 * 4096;   // 49*512
    float* cbx  = w7 + 49 * 512;                   // 512
    u16* attbf = xbf;                              // alias (x dead after qkv)

    // 1) fused prep + x conversion
    prep_all_kernel<<<610, 256, 0, stream>>>(
        Wqkv, Wproj, ck3, cb3, ck5, cb5, ck7, cb7, wqT, wpT, w7, cbx);
    convert_x_kernel<<<(int)(PLANE / 8 / 256), 256, 0, stream>>>(x, xbf);

    // 2) qkv GEMM -> bf16 q/k/v planes (coalesced LDS epilogue)
    {
        int nwg = 12 * (MP / 128);   // 3096
        gemm_bf16_kernel<0, 1536, 12><<<nwg, 256, 0, stream>>>(xbf, wqT, bqkv, qbf, nwg);
    }
    // 3) ksv partials (no-max, fused colsum) + transpose-reduce -> bf16 ksvT
    {
        dim3 grid(BB * HH, 4);
        ksv_part_kernel<<<grid, 256, 0, stream>>>(kbf, vbf, part, psum);
        ksv_reduceT_kernel<<<256 * 4096 / 4 / 256, 256, 0, stream>>>(part, psum, ksvT);
    }
    // 4) fused factor+conv+n0 -> attbf
    {
        dim3 grid(9, BB * HH);
        attn_ev_kernel<<<grid, 256, 0, stream>>>(qbf, vbf, ksvT, w7, cbx, attbf);
    }
    // 5) proj GEMM -> out
    {
        int nwg = 4 * (MP / 128);    // 1032
        gemm_bf16_kernel<1, 512, 4><<<nwg, 256, 0, stream>>>(attbf, wpT, bproj, out, nwg);
    }
}